// Round 17
// baseline (217.511 us; speedup 1.0000x reference)
//
#include <hip/hip_runtime.h>

// Problem sizes (fixed)
#define NB   32
#define CI   256
#define HH   56
#define WW   56
#define PL   128
#define HO   28
#define WO   28
#define CO   512
#define NPIX (HH * WW)   // 3136
#define NOUT (HO * WO)   // 784
#define FIXCAP 65536u
#define MARGIN1 3e-3f
#define MARGIN3 6e-3f

typedef unsigned long long u64;
typedef __attribute__((ext_vector_type(8))) short short8v;
typedef __attribute__((ext_vector_type(4))) float f32x4;

// ============ exact f32 -> (hi,lo) bf16 split, RNE both ============
__device__ __forceinline__ unsigned cvt_split(float f) {
  unsigned u = __float_as_uint(f);
  unsigned hi = (u + 0x7FFFu + ((u >> 16) & 1u)) >> 16;
  float r = f - __uint_as_float(hi << 16);            // exact (Sterbenz)
  unsigned ur = __float_as_uint(r);
  unsigned lo = (ur + 0x7FFFu + ((ur >> 16) & 1u)) >> 16;
  return hi | (lo << 16);
}

// ---------------- K0: pack weights + BN constants ----------------
__global__ __launch_bounds__(256) void pack_kernel(
    const float* __restrict__ W1, const float* __restrict__ W2,
    const float* __restrict__ W3, const float* __restrict__ Wsc,
    const float* __restrict__ g1, const float* __restrict__ b1,
    const float* __restrict__ m1, const float* __restrict__ v1,
    const float* __restrict__ g3, const float* __restrict__ b3,
    const float* __restrict__ m3, const float* __restrict__ v3,
    const float* __restrict__ gs, const float* __restrict__ bs,
    const float* __restrict__ ms, const float* __restrict__ vs,
    float* __restrict__ w1f, float* __restrict__ wscf,
    u64* __restrict__ w2b, u64* __restrict__ w3b,
    float* __restrict__ T1f, double* __restrict__ bn1d,
    float* __restrict__ bn3f, double* __restrict__ bn3d,
    unsigned* __restrict__ w1k, unsigned* __restrict__ wsck,
    unsigned* __restrict__ cnts) {
  int tid = blockIdx.x * 256 + threadIdx.x;
  int lane = tid & 63;
  if (tid < 32768) {
    int co = tid & 127, ci = tid >> 7;
    w1f[tid] = (W1[co * 256 + ci] >= 0.f) ? 1.0f : -1.0f;
  } else if (tid < 163840) {
    int i = tid - 32768;
    int co = i & 511, ci = i >> 9;
    wscf[i] = (Wsc[co * 256 + ci] >= 0.f) ? 1.0f : -1.0f;
  } else if (tid < 311296) {
    int wv = (tid - 163840) >> 6;       // co*18 + tap*2 + word
    int co = wv / 18, r = wv % 18;
    int tap = r >> 1, word = r & 1;
    int ci = word * 64 + lane;
    bool pred = W2[(co * 128 + ci) * 9 + tap] >= 0.f;
    u64 m = __ballot(pred);
    if (lane == 0) w2b[(co * 9 + tap) * 2 + word] = m;
  } else if (tid < 376832) {
    int wv = (tid - 311296) >> 6;       // co*2 + word
    int co = wv >> 1, word = wv & 1;
    int ci = word * 64 + lane;
    bool pred = W3[co * 128 + ci] >= 0.f;
    u64 m = __ballot(pred);
    if (lane == 0) w3b[co * 2 + word] = m;
  } else if (tid < 376960) {
    int co = tid - 376832;
    double s = (double)g1[co] / sqrt((double)v1[co] + 1e-5);
    double m = (double)m1[co], b = (double)b1[co];
    bn1d[co] = s; bn1d[128 + co] = m; bn1d[256 + co] = b;
    T1f[co] = (float)(m - b / s);
  } else if (tid < 377472) {
    int co = tid - 376960;
    double ss = (double)gs[co] / sqrt((double)vs[co] + 1e-5);
    double s3 = (double)g3[co] / sqrt((double)v3[co] + 1e-5);
    double C = (double)bs[co] + (double)b3[co]
             - (double)ms[co] * ss - (double)m3[co] * s3;
    bn3d[co] = ss; bn3d[512 + co] = s3; bn3d[1024 + co] = C;
    bn3f[co] = (float)ss; bn3f[512 + co] = (float)s3; bn3f[1024 + co] = (float)C;
  } else if (tid < 410240) {
    int i = tid - 377472;                 // co*256 + ci, co<128
    int co = i >> 8, ci = i & 255;
    unsigned b = (W1[co * 256 + ci] >= 0.f) ? 0x3F80u : 0xBF80u;
    int kst = ci >> 5, u = ci & 31;
    w1k[(size_t)kst * (128 * 32) + co * 32 + (u ^ ((co & 7) << 2))] = b | (b << 16);
  } else if (tid < 541312) {
    int i = tid - 410240;                 // co*256 + ci, co<512
    int co = i >> 8, ci = i & 255;
    unsigned b = (Wsc[co * 256 + ci] >= 0.f) ? 0x3F80u : 0xBF80u;
    int kst = ci >> 5, u = ci & 31;
    wsck[(size_t)kst * (512 * 32) + co * 32 + (u ^ ((co & 7) << 2))] = b | (b << 16);
  } else if (tid < 541314) {
    cnts[tid - 541312] = 0;
  }
}

// ============ f64 recheck paths (overflow/fallback only) ============
__device__ __noinline__ bool recheck_conv1(const float* __restrict__ xg,
                                           const float* __restrict__ w1f,
                                           const double* __restrict__ bn1d,
                                           int co) {
  double a = 0.0;
  for (int ci = 0; ci < 256; ++ci)
    a = fma((double)w1f[ci * 128 + co], (double)xg[(size_t)ci * NPIX], a);
  double val = (a - bn1d[128 + co]) * bn1d[co] + bn1d[256 + co];
  return val >= 0.0;
}

__device__ __noinline__ bool recheck_sc3(const float* __restrict__ xg,
                                         const float* __restrict__ wscf,
                                         const double* __restrict__ bn3d,
                                         int co, int y3) {
  double a = 0.0;
  for (int ci = 0; ci < 256; ++ci)
    a = fma((double)wscf[ci * 512 + co], (double)xg[(size_t)ci * NPIX], a);
  double val = a * bn3d[co] + (double)y3 * bn3d[512 + co] + bn3d[1024 + co];
  return val >= 0.0;
}

// ---------------- K1: conv1 GEMM — SINGLE-WAVE blocks, zero barriers -------
// wave = 32co x 64px, K=512. B staged in wave-private LDS (per-wave in-order
// LDS => no syncs). A-frags from L2-hot w1k. cw==0 wave emits xTk2.
__global__ __launch_bounds__(64) void conv1_mfma_kernel(
    const float* __restrict__ x, const unsigned* __restrict__ w1k,
    const float* __restrict__ w1f,
    const float* __restrict__ T1f, const double* __restrict__ bn1d,
    uint2* __restrict__ fix1, unsigned* __restrict__ cnts,
    unsigned* __restrict__ a1b32, unsigned* __restrict__ xTk2) {
  __shared__ unsigned ldsB[2048];       // 8 KB wave-private

  int bid = (int)blockIdx.x;
  int cw = bid & 3; int r = bid >> 2;
  int pxt = r % 49, n = r / 49;
  int px0 = pxt * 64;
  int t = threadIdx.x;
  int l16 = t >> 4, llo = t & 15;
  int sA = (llo & 7) << 2;
  int co0 = cw * 32;

  const float* xb = x + (size_t)n * CI * NPIX + px0;
  const unsigned* wb = w1k + (size_t)(co0 + llo) * 32;
  int offA[2][2];
#pragma unroll
  for (int cf = 0; cf < 2; ++cf)
#pragma unroll
    for (int ks = 0; ks < 2; ++ks)
      offA[cf][ks] = cf * 512 + ((ks * 16 + l16 * 4) ^ sA);

  int q = t & 15, ub = t >> 4;          // px-quad, u-base
  int pxq = q * 4;
  int sBw[4];
#pragma unroll
  for (int j = 0; j < 4; ++j) sBw[j] = (((pxq + j) >> 1) & 7) << 2;

  f32x4 acc[2][4] = {};

  for (int kst = 0; kst < 8; ++kst) {
    // A-frags (L2-hot)
    short8v aF[2][2];
#pragma unroll
    for (int cf = 0; cf < 2; ++cf)
#pragma unroll
      for (int ks = 0; ks < 2; ++ks)
        aF[cf][ks] = *(const short8v*)(wb + kst * 4096 + offA[cf][ks]);
    // stage B: 8 float4 x-loads per thread -> cvt -> private LDS
#pragma unroll
    for (int i = 0; i < 8; ++i) {
      int u = ub + 4 * i;
      float4 v = *(const float4*)(xb + (size_t)(kst * 32 + u) * NPIX + pxq);
      unsigned wd[4];
      wd[0] = cvt_split(v.x); wd[1] = cvt_split(v.y);
      wd[2] = cvt_split(v.z); wd[3] = cvt_split(v.w);
#pragma unroll
      for (int j = 0; j < 4; ++j)
        ldsB[(pxq + j) * 32 + (u ^ sBw[j])] = wd[j];
    }
    // MFMA (same-wave LDS ordering guarantees visibility, no barrier)
#pragma unroll
    for (int ks = 0; ks < 2; ++ks) {
      int kb = ks * 16 + l16 * 4;
#pragma unroll
      for (int pf = 0; pf < 4; ++pf) {
        int pxl = pf * 16 + llo;
        int sB = ((pxl >> 1) & 7) << 2;
        short8v bv = *(const short8v*)(&ldsB[pxl * 32 + (kb ^ sB)]);
        acc[0][pf] = __builtin_amdgcn_mfma_f32_16x16x32_bf16(aF[0][ks], bv, acc[0][pf], 0, 0, 0);
        acc[1][pf] = __builtin_amdgcn_mfma_f32_16x16x32_bf16(aF[1][ks], bv, acc[1][pf], 0, 0, 0);
      }
    }
    // xTk2 side product (one co-wave only), coalesced 16B stores
    if (cw == 0) {
      unsigned* d2 = xTk2 + (size_t)(n * 8 + kst) * NOUT * 32;
#pragma unroll
      for (int it2 = 0; it2 < 4; ++it2) {
        int s = it2 * 64 + t;
        int bg = s & 7, be = s >> 3;
        int bp = px0 + 2 * be;
        int bh = bp / WW;
        if ((bh & 1) == 0) {
          int bpl = (bh >> 1) * WO + (bp % WW) / 2;
          uint4 o = *(const uint4*)(&ldsB[(2 * be) * 32 + ((4 * bg) ^ ((be & 7) << 2))]);
          *(uint4*)(d2 + (size_t)bpl * 32 + ((4 * bg) ^ ((bpl & 7) << 2))) = o;
        }
      }
    }
  }

  // epilogue: sign + margin -> private-LDS bytes -> one u32 per px
  unsigned char* ldsS = (unsigned char*)ldsB;     // reuse (in-order safe)
  float Tv[2][4];
#pragma unroll
  for (int cf = 0; cf < 2; ++cf)
#pragma unroll
    for (int rr = 0; rr < 4; ++rr)
      Tv[cf][rr] = T1f[co0 + cf * 16 + l16 * 4 + rr];

#pragma unroll
  for (int cf = 0; cf < 2; ++cf)
#pragma unroll
    for (int pf = 0; pf < 4; ++pf) {
      int px_l = pf * 16 + llo;
#pragma unroll
      for (int rr = 0; rr < 4; ++rr) {
        int co_loc = cf * 16 + l16 * 4 + rr;
        int co = co0 + co_loc;
        float d = acc[cf][pf][rr] - Tv[cf][rr];
        bool pos = d >= 0.f;
        if (__builtin_fabsf(d) < MARGIN1) {
          unsigned idx = atomicAdd(&cnts[0], 1u);
          if (idx < FIXCAP) fix1[idx] = make_uint2((unsigned)(n * NPIX + px0 + px_l),
                                                   (unsigned)co);
          else pos = recheck_conv1(x + (size_t)n * CI * NPIX + px0 + px_l,
                                   w1f, bn1d, co);
        }
        ldsS[px_l * 32 + (co_loc ^ ((px_l & 7) << 2))] = pos ? 1 : 0;
      }
    }

  {
    int px = t;                          // 64 px, one per lane
    const unsigned* ls = (const unsigned*)ldsS;
    unsigned word32 = 0;
#pragma unroll
    for (int wi = 0; wi < 8; ++wi) {
      unsigned v = ls[px * 8 + (wi ^ (px & 7))];
      unsigned nib = (((v & 0x01010101u) * 0x01020408u) >> 24) & 0xFu;
      word32 |= nib << (4 * wi);
    }
    a1b32[(size_t)(n * NPIX + px0 + px) * 4 + cw] = word32;
  }
}

// ---------------- F1: wave-parallel f64 fixup of a1b bits ----------------
__global__ __launch_bounds__(256) void fixup1_kernel(
    const float* __restrict__ x, const float* __restrict__ w1f,
    const double* __restrict__ bn1d, const uint2* __restrict__ fix1,
    const unsigned* __restrict__ cnts, u64* __restrict__ a1b) {
  unsigned cnt = cnts[0]; if (cnt > FIXCAP) cnt = FIXCAP;
  int nw = gridDim.x * 4;
  int gw = blockIdx.x * 4 + (threadIdx.x >> 6);
  int lane = threadIdx.x & 63;
  for (unsigned i = gw; i < cnt; i += nw) {
    uint2 it = fix1[i];
    int np = (int)it.x, co = (int)it.y;
    int n = np / NPIX, p = np % NPIX;
    const float* xg = x + (size_t)n * CI * NPIX + p;
    double s = 0.0;
#pragma unroll
    for (int j = 0; j < 4; ++j) {
      int ci = lane * 4 + j;
      s = fma((double)w1f[ci * 128 + co], (double)xg[(size_t)ci * NPIX], s);
    }
    for (int off = 32; off; off >>= 1) s += __shfl_down(s, off);
    if (lane == 0) {
      double val = (s - bn1d[128 + co]) * bn1d[co] + bn1d[256 + co];
      u64* ap = a1b + (size_t)np * 2 + (co >> 6);
      u64 bit = 1ull << (co & 63);
      if (val >= 0.0) atomicOr(ap, bit); else atomicAnd(ap, ~bit);
    }
  }
}

// ---------------- K2: conv2 (3x3 s2 p1, XNOR-popcount) + bn2 + sign --------
__global__ __launch_bounds__(256) void conv2_kernel(
    const u64* __restrict__ a1b, const u64* __restrict__ w2b,
    const float* __restrict__ g2, const float* __restrict__ b2,
    const float* __restrict__ m2, const float* __restrict__ v2,
    u64* __restrict__ a2b) {
  __shared__ u64 lw2[128 * 9 * 2];   // 18432 B
  int t = threadIdx.x;
  for (int k = 0; k < 9; ++k) lw2[t * 9 + k] = w2b[t * 9 + k];
  __syncthreads();

  int bid = (int)blockIdx.x;
  int l = (bid & 7) * 784 + (bid >> 3);
  int p = l * 4 + (t >> 6);
  int lane = t & 63;
  int n = p / NOUT, r = p % NOUT;
  int ho = r / WO, wo = r % WO;

  int y0 = 0, y1 = 0;
  for (int kh = 0; kh < 3; ++kh) {
    int ih = 2 * ho - 1 + kh;
    if (ih < 0) continue;
    for (int kw = 0; kw < 3; ++kw) {
      int iw = 2 * wo - 1 + kw;
      if (iw < 0) continue;
      const u64* ap = a1b + ((size_t)(n * HH + ih) * WW + iw) * 2;
      u64 a0 = ap[0], a1v = ap[1];
      int tap = kh * 3 + kw;
      u64 wa = lw2[lane * 18 + tap * 2], wb = lw2[lane * 18 + tap * 2 + 1];
      y0 += 128 - 2 * (__popcll(a0 ^ wa) + __popcll(a1v ^ wb));
      wa = lw2[(lane + 64) * 18 + tap * 2]; wb = lw2[(lane + 64) * 18 + tap * 2 + 1];
      y1 += 128 - 2 * (__popcll(a0 ^ wa) + __popcll(a1v ^ wb));
    }
  }

  int co = lane;
  double inv = 1.0 / sqrt((double)v2[co] + 1e-5);
  bool c0 = (((double)y0 - (double)m2[co]) * ((double)g2[co] * inv) + (double)b2[co]) >= 0.0;
  co = lane + 64;
  inv = 1.0 / sqrt((double)v2[co] + 1e-5);
  bool c1 = (((double)y1 - (double)m2[co]) * ((double)g2[co] * inv) + (double)b2[co]) >= 0.0;

  u64 word0 = __ballot(c0);
  u64 word1 = __ballot(c1);
  if (lane == 0) {
    a2b[(size_t)p * 2] = word0;
    a2b[(size_t)p * 2 + 1] = word1;
  }
}

// ---------------- K3: shortcut GEMM — SINGLE-WAVE blocks, no loop LDS ------
// wave = 32co x 112px; B frags read directly from dense xTk2 (L2),
// A from wsck; zero barriers. Epilogue via 3.5KB private LDS -> coalesced.
__global__ __launch_bounds__(64) void sc3_mfma_kernel(
    const unsigned* __restrict__ xTk2, const unsigned* __restrict__ wsck,
    const u64* __restrict__ a2b, const u64* __restrict__ w3b,
    const float* __restrict__ bn3f,
    uint2* __restrict__ fix3, unsigned* __restrict__ cnts,
    float* __restrict__ out) {
  __shared__ unsigned char ldsS[32 * 112];   // 3584 B wave-private

  int bid = (int)blockIdx.x;
  int cw = bid & 15; int r = bid >> 4;
  int pxt = r % 7, n = r / 7;
  int px0 = pxt * 112, co0 = cw * 32;
  int t = threadIdx.x;
  int l16 = t >> 4, llo = t & 15;
  int sA = (llo & 7) << 2;

  const unsigned* wb = wsck + (size_t)(co0 + llo) * 32;
  int offA[2][2];
#pragma unroll
  for (int cf = 0; cf < 2; ++cf)
#pragma unroll
    for (int ks = 0; ks < 2; ++ks)
      offA[cf][ks] = cf * 512 + ((ks * 16 + l16 * 4) ^ sA);

  f32x4 acc[2][7] = {};

  for (int kst = 0; kst < 8; ++kst) {
    short8v aF[2][2];
#pragma unroll
    for (int cf = 0; cf < 2; ++cf)
#pragma unroll
      for (int ks = 0; ks < 2; ++ks)
        aF[cf][ks] = *(const short8v*)(wb + kst * 16384 + offA[cf][ks]);
    const unsigned* gb = xTk2 + ((size_t)(n * 8 + kst) * NOUT + px0) * 32;
#pragma unroll
    for (int ks = 0; ks < 2; ++ks) {
      int kb = ks * 16 + l16 * 4;
#pragma unroll
      for (int pf = 0; pf < 7; ++pf) {
        short8v bv = *(const short8v*)(gb + (size_t)(pf * 16 + llo) * 32 + (kb ^ sA));
        acc[0][pf] = __builtin_amdgcn_mfma_f32_16x16x32_bf16(aF[0][ks], bv, acc[0][pf], 0, 0, 0);
        acc[1][pf] = __builtin_amdgcn_mfma_f32_16x16x32_bf16(aF[1][ks], bv, acc[1][pf], 0, 0, 0);
      }
    }
  }

  // epilogue: conv3 popcount + fused BNs + sign (+ rare list-append)
  int pl[7];
  u64 a20[7], a21[7];
#pragma unroll
  for (int pf = 0; pf < 7; ++pf) {
    pl[pf] = px0 + pf * 16 + llo;
    const u64* ap = a2b + (size_t)(n * NOUT + pl[pf]) * 2;
    a20[pf] = ap[0]; a21[pf] = ap[1];
  }

#pragma unroll
  for (int cf = 0; cf < 2; ++cf) {
    float ssv[4], s3v[4], Cv[4];
    u64 w30[4], w31[4];
#pragma unroll
    for (int rr = 0; rr < 4; ++rr) {
      int co = co0 + cf * 16 + l16 * 4 + rr;
      ssv[rr] = bn3f[co]; s3v[rr] = bn3f[512 + co]; Cv[rr] = bn3f[1024 + co];
      w30[rr] = w3b[co * 2]; w31[rr] = w3b[co * 2 + 1];
    }
#pragma unroll
    for (int pf = 0; pf < 7; ++pf) {
#pragma unroll
      for (int rr = 0; rr < 4; ++rr) {
        int co_loc = cf * 16 + l16 * 4 + rr;
        int co = co0 + co_loc;
        int y3 = 128 - 2 * (int)(__popcll(a20[pf] ^ w30[rr]) +
                                 __popcll(a21[pf] ^ w31[rr]));
        float val = fmaf(acc[cf][pf][rr], ssv[rr],
                         fmaf((float)y3, s3v[rr], Cv[rr]));
        bool pos = val >= 0.f;
        if (__builtin_fabsf(val) < MARGIN3) {
          unsigned idx = atomicAdd(&cnts[1], 1u);
          if (idx < FIXCAP)
            fix3[idx] = make_uint2((unsigned)(n * NOUT + pl[pf]),
                                   (unsigned)co | ((unsigned)(y3 + 256) << 16));
        }
        ldsS[co_loc * 112 + (pf * 16 + llo)] = pos ? 1 : 0;
      }
    }
  }

  if (t < 56) {
    int f4 = t % 28, cg = t / 28;       // cg 0..1
    const unsigned* ls32 = (const unsigned*)ldsS;
#pragma unroll
    for (int j = 0; j < 16; ++j) {
      int co_loc = cg * 16 + j;
      unsigned wbyte = ls32[co_loc * 28 + f4];
      float4 o;
      o.x = (wbyte & 0xFFu) ? 1.f : -1.f;
      o.y = (wbyte & 0xFF00u) ? 1.f : -1.f;
      o.z = (wbyte & 0xFF0000u) ? 1.f : -1.f;
      o.w = (wbyte & 0xFF000000u) ? 1.f : -1.f;
      *(float4*)(out + ((size_t)(n * CO + co0 + co_loc)) * NOUT
                 + px0 + f4 * 4) = o;
    }
  }
}

// ---------------- F3: wave-parallel f64 fixup of out values ----------------
__global__ __launch_bounds__(256) void fixup3_kernel(
    const float* __restrict__ x, const float* __restrict__ wscf,
    const double* __restrict__ bn3d, const uint2* __restrict__ fix3,
    const unsigned* __restrict__ cnts, float* __restrict__ out) {
  unsigned cnt = cnts[1]; if (cnt > FIXCAP) cnt = FIXCAP;
  int nw = gridDim.x * 4;
  int gw = blockIdx.x * 4 + (threadIdx.x >> 6);
  int lane = threadIdx.x & 63;
  for (unsigned i = gw; i < cnt; i += nw) {
    uint2 it = fix3[i];
    int npl = (int)it.x;
    int co = (int)(it.y & 0xFFFFu);
    int y3 = (int)(it.y >> 16) - 256;
    int n = npl / NOUT, pl = npl % NOUT;
    int ho = pl / WO, wo = pl % WO;
    const float* xg = x + (size_t)n * CI * NPIX + ho * 112 + wo * 2;
    double s = 0.0;
#pragma unroll
    for (int j = 0; j < 4; ++j) {
      int ci = lane * 4 + j;
      s = fma((double)wscf[ci * 512 + co], (double)xg[(size_t)ci * NPIX], s);
    }
    for (int off = 32; off; off >>= 1) s += __shfl_down(s, off);
    if (lane == 0) {
      double val = s * bn3d[co] + (double)y3 * bn3d[512 + co] + bn3d[1024 + co];
      out[(size_t)(n * CO + co) * NOUT + pl] = (val >= 0.0) ? 1.0f : -1.0f;
    }
  }
}

// ================= fallback (R2) f32-VALU kernels =================
__global__ __launch_bounds__(256) void conv1_kernel(
    const float* __restrict__ x, const float* __restrict__ w1f,
    const float* __restrict__ T1f, const double* __restrict__ bn1d,
    u64* __restrict__ a1b) {
  __shared__ float4 xrow4[128 * WW / 4];
  __shared__ unsigned char pk[WW * 32];
  float* xrow = (float*)xrow4;

  int bid = blockIdx.x;
  int n = bid / HH, h = bid % HH;
  int t = threadIdx.x;
  int cg = t & 31, wg = t >> 5;
  int co0 = cg * 4, w0 = wg * 7;

  float acc[4][7];
#pragma unroll
  for (int c = 0; c < 4; ++c)
#pragma unroll
    for (int j = 0; j < 7; ++j) acc[c][j] = 0.f;

  for (int chunk = 0; chunk < 2; ++chunk) {
    const float4* xsrc = (const float4*)(x + (size_t)n * CI * NPIX
                                         + (size_t)chunk * 128 * NPIX + h * WW);
    for (int i = 0; i < 7; ++i) {
      int idx = i * 256 + t;
      int ci = idx / 14, f = idx % 14;
      xrow4[ci * 14 + f] = xsrc[(size_t)ci * (NPIX / 4) + f];
    }
    __syncthreads();

    const float* wp = w1f + (size_t)chunk * 128 * 128 + co0;
#pragma unroll 2
    for (int ci = 0; ci < 128; ++ci) {
      float4 wv = *(const float4*)(wp + ci * 128);
      const float* xr = xrow + ci * WW + w0;
#pragma unroll
      for (int j = 0; j < 7; ++j) {
        float xv = xr[j];
        acc[0][j] = fmaf(wv.x, xv, acc[0][j]);
        acc[1][j] = fmaf(wv.y, xv, acc[1][j]);
        acc[2][j] = fmaf(wv.z, xv, acc[2][j]);
        acc[3][j] = fmaf(wv.w, xv, acc[3][j]);
      }
    }
    __syncthreads();
  }

  float Tv[4];
#pragma unroll
  for (int c = 0; c < 4; ++c) Tv[c] = T1f[co0 + c];

  for (int j = 0; j < 7; ++j) {
    unsigned nib = 0;
    for (int c = 0; c < 4; ++c) {
      float d = acc[c][j] - Tv[c];
      bool pos;
      if (__builtin_fabsf(d) >= 1e-2f) pos = d >= 0.f;
      else pos = recheck_conv1(x + (size_t)n * CI * NPIX + h * WW + (w0 + j),
                               w1f, bn1d, co0 + c);
      nib |= ((unsigned)pos) << c;
    }
    pk[(w0 + j) * 32 + cg] = (unsigned char)nib;
  }
  __syncthreads();

  if (t < 112) {
    int w = t >> 1, half = t & 1;
    u64 word = 0;
    for (int k = 0; k < 16; ++k)
      word |= ((u64)pk[w * 32 + half * 16 + k]) << (4 * k);
    a1b[((size_t)(n * HH + h) * WW + w) * 2 + half] = word;
  }
}

__global__ __launch_bounds__(256) void sc3_kernel(
    const float* __restrict__ x, const float* __restrict__ wscf,
    const u64* __restrict__ a2b, const u64* __restrict__ w3b,
    const float* __restrict__ bn3f, const double* __restrict__ bn3d,
    float* __restrict__ out) {
  __shared__ float4 xrow4[128 * WW / 4];
  __shared__ u64 a2row[WO * 2];
  float* xrow = (float*)xrow4;

  int bid = blockIdx.x;
  int half = bid & 1;
  int tmp = bid >> 1;
  int n = tmp / HO, ho = tmp % HO;
  int t = threadIdx.x;
  int cg = t & 63, wg = t >> 6;
  int co0 = half * 256 + cg * 4, w0 = wg * 7;

  if (t < 56)
    a2row[t] = a2b[((size_t)(n * HO + ho) * WO + (t >> 1)) * 2 + (t & 1)];

  float acc[4][7];
#pragma unroll
  for (int c = 0; c < 4; ++c)
#pragma unroll
    for (int j = 0; j < 7; ++j) acc[c][j] = 0.f;

  for (int chunk = 0; chunk < 2; ++chunk) {
    const float4* xsrc = (const float4*)(x + (size_t)n * CI * NPIX
                                         + (size_t)chunk * 128 * NPIX
                                         + (2 * ho) * WW);
    for (int i = 0; i < 7; ++i) {
      int idx = i * 256 + t;
      int ci = idx / 14, f = idx % 14;
      xrow4[ci * 14 + f] = xsrc[(size_t)ci * (NPIX / 4) + f];
    }
    __syncthreads();

    const float* wp = wscf + (size_t)chunk * 128 * 512 + co0;
#pragma unroll 2
    for (int ci = 0; ci < 128; ++ci) {
      float4 wv = *(const float4*)(wp + ci * 512);
      const float* xr = xrow + ci * WW + 2 * w0;
#pragma unroll
      for (int j = 0; j < 7; ++j) {
        float xv = xr[2 * j];
        acc[0][j] = fmaf(wv.x, xv, acc[0][j]);
        acc[1][j] = fmaf(wv.y, xv, acc[1][j]);
        acc[2][j] = fmaf(wv.z, xv, acc[2][j]);
        acc[3][j] = fmaf(wv.w, xv, acc[3][j]);
      }
    }
    __syncthreads();
  }

#pragma unroll
  for (int c = 0; c < 4; ++c) {
    int co = co0 + c;
    u64 w30 = w3b[co * 2], w31 = w3b[co * 2 + 1];
    float ssf = bn3f[co], s3f = bn3f[512 + co], Cf = bn3f[1024 + co];
    float* op = out + ((size_t)(n * CO + co) * NOUT) + ho * WO + w0;
    for (int j = 0; j < 7; ++j) {
      int wo = w0 + j;
      u64 a0 = a2row[wo * 2], a1v = a2row[wo * 2 + 1];
      int y3 = 128 - 2 * (int)(__popcll(a0 ^ w30) + __popcll(a1v ^ w31));
      float val = fmaf(acc[c][j], ssf, fmaf((float)y3, s3f, Cf));
      bool pos;
      if (__builtin_fabsf(val) >= 2e-2f) pos = val >= 0.f;
      else pos = recheck_sc3(x + (size_t)n * CI * NPIX + (2 * ho) * WW + 2 * wo,
                             wscf, bn3d, co, y3);
      op[j] = pos ? 1.0f : -1.0f;
    }
  }
}

extern "C" void kernel_launch(void* const* d_in, const int* in_sizes, int n_in,
                              void* d_out, int out_size, void* d_ws, size_t ws_size,
                              hipStream_t stream) {
  const float* x   = (const float*)d_in[0];
  const float* W1  = (const float*)d_in[1];
  const float* W2  = (const float*)d_in[2];
  const float* W3  = (const float*)d_in[3];
  const float* Wsc = (const float*)d_in[4];
  const float* g1 = (const float*)d_in[5],  *b1 = (const float*)d_in[6];
  const float* m1 = (const float*)d_in[7],  *v1 = (const float*)d_in[8];
  const float* g2 = (const float*)d_in[9],  *b2 = (const float*)d_in[10];
  const float* m2 = (const float*)d_in[11], *v2 = (const float*)d_in[12];
  const float* g3 = (const float*)d_in[13], *b3 = (const float*)d_in[14];
  const float* m3 = (const float*)d_in[15], *v3 = (const float*)d_in[16];
  const float* gs = (const float*)d_in[17], *bs = (const float*)d_in[18];
  const float* ms = (const float*)d_in[19], *vs = (const float*)d_in[20];

  char* ws = (char*)d_ws;
  float*  w1f  = (float*)(ws + 0);           // 131072
  float*  wscf = (float*)(ws + 131072);      // 524288
  u64*    a1b  = (u64*)(ws + 655360);        // 1605632
  u64*    a2b  = (u64*)(ws + 2260992);       // 401408
  u64*    w2b  = (u64*)(ws + 2662400);       // 18432
  u64*    w3b  = (u64*)(ws + 2680832);       // 8192
  float*  T1f  = (float*)(ws + 2689024);     // 512
  double* bn1d = (double*)(ws + 2689536);    // 3072
  float*  bn3f = (float*)(ws + 2692608);     // 6144
  double* bn3d = (double*)(ws + 2698752);    // 12288
  unsigned* w1k  = (unsigned*)(ws + 2711040);    // 131072
  unsigned* wsck = (unsigned*)(ws + 2842112);    // 524288
  unsigned* xTk2 = (unsigned*)(ws + 3366400);    // 25690112
  uint2*    fix1 = (uint2*)(ws + 29056512);      // 524288
  uint2*    fix3 = (uint2*)(ws + 29580800);      // 524288
  unsigned* cnts = (unsigned*)(ws + 30105088);   // 256
  const size_t required = 30105344ull;           // ~28.7 MiB
  float* out = (float*)d_out;

  bool mfma_path = (ws_size >= required);
  if (!mfma_path) {   // alias mfma-only arrays into a1b region (unused then)
    w1k  = (unsigned*)a1b;
    wsck = (unsigned*)a1b + 32768;
    cnts = (unsigned*)a1b + 32768 + 131072;
  }

  hipLaunchKernelGGL(pack_kernel, dim3(2115), dim3(256), 0, stream,
                     W1, W2, W3, Wsc, g1, b1, m1, v1, g3, b3, m3, v3,
                     gs, bs, ms, vs, w1f, wscf, w2b, w3b, T1f, bn1d, bn3f, bn3d,
                     w1k, wsck, cnts);
  if (mfma_path) {
    hipLaunchKernelGGL(conv1_mfma_kernel, dim3(NB * 49 * 4), dim3(64), 0, stream,
                       x, w1k, w1f, T1f, bn1d, fix1, cnts, (unsigned*)a1b, xTk2);
    hipLaunchKernelGGL(fixup1_kernel, dim3(256), dim3(256), 0, stream,
                       x, w1f, bn1d, fix1, cnts, a1b);
    hipLaunchKernelGGL(conv2_kernel, dim3(NB * NOUT / 4), dim3(256), 0, stream,
                       a1b, w2b, g2, b2, m2, v2, a2b);
    hipLaunchKernelGGL(sc3_mfma_kernel, dim3(NB * 7 * 16), dim3(64), 0, stream,
                       xTk2, wsck, a2b, w3b, bn3f, fix3, cnts, out);
    hipLaunchKernelGGL(fixup3_kernel, dim3(256), dim3(256), 0, stream,
                       x, wscf, bn3d, fix3, cnts, out);
  } else {
    hipLaunchKernelGGL(conv1_kernel, dim3(NB * HH), dim3(256), 0, stream,
                       x, w1f, T1f, bn1d, a1b);
    hipLaunchKernelGGL(conv2_kernel, dim3(NB * NOUT / 4), dim3(256), 0, stream,
                       a1b, w2b, g2, b2, m2, v2, a2b);
    hipLaunchKernelGGL(sc3_kernel, dim3(NB * HO * 2), dim3(256), 0, stream,
                       x, wscf, a2b, w3b, bn3f, bn3d, out);
  }
}

// Round 18
// 187.562 us; speedup vs baseline: 1.1597x; 1.1597x over previous
//
#include <hip/hip_runtime.h>

// Problem sizes (fixed)
#define NB   32
#define CI   256
#define HH   56
#define WW   56
#define PL   128
#define HO   28
#define WO   28
#define CO   512
#define NPIX (HH * WW)   // 3136
#define NOUT (HO * WO)   // 784
#define FIXCAP 65536u
#define MARGIN1 3e-3f
#define MARGIN3 6e-3f

typedef unsigned long long u64;
typedef __attribute__((ext_vector_type(8))) short short8v;
typedef __attribute__((ext_vector_type(4))) float f32x4;

// ============ exact f32 -> (hi,lo) bf16 split, RNE both ============
__device__ __forceinline__ unsigned cvt_split(float f) {
  unsigned u = __float_as_uint(f);
  unsigned hi = (u + 0x7FFFu + ((u >> 16) & 1u)) >> 16;
  float r = f - __uint_as_float(hi << 16);            // exact (Sterbenz)
  unsigned ur = __float_as_uint(r);
  unsigned lo = (ur + 0x7FFFu + ((ur >> 16) & 1u)) >> 16;
  return hi | (lo << 16);
}

// ---------------- K0: pack weights + BN constants ----------------
__global__ __launch_bounds__(256) void pack_kernel(
    const float* __restrict__ W1, const float* __restrict__ W2,
    const float* __restrict__ W3, const float* __restrict__ Wsc,
    const float* __restrict__ g1, const float* __restrict__ b1,
    const float* __restrict__ m1, const float* __restrict__ v1,
    const float* __restrict__ g3, const float* __restrict__ b3,
    const float* __restrict__ m3, const float* __restrict__ v3,
    const float* __restrict__ gs, const float* __restrict__ bs,
    const float* __restrict__ ms, const float* __restrict__ vs,
    float* __restrict__ w1f, float* __restrict__ wscf,
    u64* __restrict__ w2b, u64* __restrict__ w3b,
    float* __restrict__ T1f, double* __restrict__ bn1d,
    float* __restrict__ bn3f, double* __restrict__ bn3d,
    unsigned* __restrict__ w1k, unsigned* __restrict__ wsck,
    unsigned* __restrict__ cnts) {
  int tid = blockIdx.x * 256 + threadIdx.x;
  int lane = tid & 63;
  if (tid < 32768) {
    int co = tid & 127, ci = tid >> 7;
    w1f[tid] = (W1[co * 256 + ci] >= 0.f) ? 1.0f : -1.0f;
  } else if (tid < 163840) {
    int i = tid - 32768;
    int co = i & 511, ci = i >> 9;
    wscf[i] = (Wsc[co * 256 + ci] >= 0.f) ? 1.0f : -1.0f;
  } else if (tid < 311296) {
    int wv = (tid - 163840) >> 6;       // co*18 + tap*2 + word
    int co = wv / 18, r = wv % 18;
    int tap = r >> 1, word = r & 1;
    int ci = word * 64 + lane;
    bool pred = W2[(co * 128 + ci) * 9 + tap] >= 0.f;
    u64 m = __ballot(pred);
    if (lane == 0) w2b[(co * 9 + tap) * 2 + word] = m;
  } else if (tid < 376832) {
    int wv = (tid - 311296) >> 6;       // co*2 + word
    int co = wv >> 1, word = wv & 1;
    int ci = word * 64 + lane;
    bool pred = W3[co * 128 + ci] >= 0.f;
    u64 m = __ballot(pred);
    if (lane == 0) w3b[co * 2 + word] = m;
  } else if (tid < 376960) {
    int co = tid - 376832;
    double s = (double)g1[co] / sqrt((double)v1[co] + 1e-5);
    double m = (double)m1[co], b = (double)b1[co];
    bn1d[co] = s; bn1d[128 + co] = m; bn1d[256 + co] = b;
    T1f[co] = (float)(m - b / s);
  } else if (tid < 377472) {
    int co = tid - 376960;
    double ss = (double)gs[co] / sqrt((double)vs[co] + 1e-5);
    double s3 = (double)g3[co] / sqrt((double)v3[co] + 1e-5);
    double C = (double)bs[co] + (double)b3[co]
             - (double)ms[co] * ss - (double)m3[co] * s3;
    bn3d[co] = ss; bn3d[512 + co] = s3; bn3d[1024 + co] = C;
    bn3f[co] = (float)ss; bn3f[512 + co] = (float)s3; bn3f[1024 + co] = (float)C;
  } else if (tid < 410240) {
    int i = tid - 377472;                 // co*256 + ci, co<128
    int co = i >> 8, ci = i & 255;
    unsigned b = (W1[co * 256 + ci] >= 0.f) ? 0x3F80u : 0xBF80u;
    int kst = ci >> 5, u = ci & 31;
    w1k[(size_t)kst * (128 * 32) + co * 32 + (u ^ ((co & 7) << 2))] = b | (b << 16);
  } else if (tid < 541312) {
    int i = tid - 410240;                 // co*256 + ci, co<512
    int co = i >> 8, ci = i & 255;
    unsigned b = (Wsc[co * 256 + ci] >= 0.f) ? 0x3F80u : 0xBF80u;
    int kst = ci >> 5, u = ci & 31;
    wsck[(size_t)kst * (512 * 32) + co * 32 + (u ^ ((co & 7) << 2))] = b | (b << 16);
  } else if (tid < 541314) {
    cnts[tid - 541312] = 0;
  }
}

// ============ f64 recheck paths (overflow/fallback only) ============
__device__ __noinline__ bool recheck_conv1(const float* __restrict__ xg,
                                           const float* __restrict__ w1f,
                                           const double* __restrict__ bn1d,
                                           int co) {
  double a = 0.0;
  for (int ci = 0; ci < 256; ++ci)
    a = fma((double)w1f[ci * 128 + co], (double)xg[(size_t)ci * NPIX], a);
  double val = (a - bn1d[128 + co]) * bn1d[co] + bn1d[256 + co];
  return val >= 0.0;
}

__device__ __noinline__ bool recheck_sc3(const float* __restrict__ xg,
                                         const float* __restrict__ wscf,
                                         const double* __restrict__ bn3d,
                                         int co, int y3) {
  double a = 0.0;
  for (int ci = 0; ci < 256; ++ci)
    a = fma((double)wscf[ci * 512 + co], (double)xg[(size_t)ci * NPIX], a);
  double val = a * bn3d[co] + (double)y3 * bn3d[512 + co] + bn3d[1024 + co];
  return val >= 0.0;
}

// ---------------- K1: conv1 — single wave, 128co x 32px, 1x traffic --------
__global__ __launch_bounds__(64) void conv1_mfma_kernel(
    const float* __restrict__ x, const unsigned* __restrict__ w1k,
    const float* __restrict__ w1f,
    const float* __restrict__ T1f, const double* __restrict__ bn1d,
    uint2* __restrict__ fix1, unsigned* __restrict__ cnts,
    u64* __restrict__ a1b, unsigned* __restrict__ xTk2) {
  __shared__ unsigned ldsB[1024];       // 4 KB wave-private

  int bid = (int)blockIdx.x;
  int pxt = bid % 98, n = bid / 98;
  int px0 = pxt * 32;
  int t = threadIdx.x;
  int l16 = t >> 4, llo = t & 15;
  int sA = (llo & 7) << 2;

  const float* xb = x + (size_t)n * CI * NPIX + px0;
  const unsigned* wb = w1k + (size_t)llo * 32;

  f32x4 acc[8][2] = {};

  for (int kst = 0; kst < 8; ++kst) {
    // stage B: 4 float4 x-loads/thread (8 rows x 128B per instr)
#pragma unroll
    for (int i = 0; i < 4; ++i) {
      int slot = i * 64 + t;
      int u = slot >> 3, q = slot & 7;
      int pxq = q * 4;
      float4 v = *(const float4*)(xb + (size_t)(kst * 32 + u) * NPIX + pxq);
      unsigned wd[4];
      wd[0] = cvt_split(v.x); wd[1] = cvt_split(v.y);
      wd[2] = cvt_split(v.z); wd[3] = cvt_split(v.w);
#pragma unroll
      for (int j = 0; j < 4; ++j)
        ldsB[(pxq + j) * 32 + (u ^ ((((pxq + j) >> 1) & 7) << 2))] = wd[j];
    }
    // MFMA: 8 cf x 2 pf x 2 ks (wave-private LDS: no barrier)
#pragma unroll
    for (int ks = 0; ks < 2; ++ks) {
      int kb = ks * 16 + l16 * 4;
      short8v aF[8];
#pragma unroll
      for (int cf = 0; cf < 8; ++cf)
        aF[cf] = *(const short8v*)(wb + kst * 4096 + cf * 512 + (kb ^ sA));
#pragma unroll
      for (int pf = 0; pf < 2; ++pf) {
        int pxl = pf * 16 + llo;
        int sB = ((pxl >> 1) & 7) << 2;
        short8v bv = *(const short8v*)(&ldsB[pxl * 32 + (kb ^ sB)]);
#pragma unroll
        for (int cf = 0; cf < 8; ++cf)
          acc[cf][pf] = __builtin_amdgcn_mfma_f32_16x16x32_bf16(aF[cf], bv, acc[cf][pf], 0, 0, 0);
      }
    }
    // xTk2 side product: 16 even-px x 8 u-quads = 128 uint4 -> 2/lane
    {
      unsigned* d2 = xTk2 + (size_t)(n * 8 + kst) * NOUT * 32;
#pragma unroll
      for (int it2 = 0; it2 < 2; ++it2) {
        int s = it2 * 64 + t;
        int bg = s & 7, be = s >> 3;     // u-quad, even-px idx (0..15)
        int bp = px0 + 2 * be;
        int bh = bp / WW;
        if ((bh & 1) == 0) {
          int bpl = (bh >> 1) * WO + (bp % WW) / 2;
          uint4 o = *(const uint4*)(&ldsB[(2 * be) * 32 + ((4 * bg) ^ ((be & 7) << 2))]);
          *(uint4*)(d2 + (size_t)bpl * 32 + ((4 * bg) ^ ((bpl & 7) << 2))) = o;
        }
      }
    }
  }

  // epilogue: sign + margin -> private-LDS bytes -> u64 pair per px
  unsigned char* ldsS = (unsigned char*)ldsB;     // 4096 B, in-order reuse
  float Tv[8][4];
#pragma unroll
  for (int cf = 0; cf < 8; ++cf)
#pragma unroll
    for (int rr = 0; rr < 4; ++rr)
      Tv[cf][rr] = T1f[cf * 16 + l16 * 4 + rr];

#pragma unroll
  for (int cf = 0; cf < 8; ++cf)
#pragma unroll
    for (int pf = 0; pf < 2; ++pf) {
      int px_l = pf * 16 + llo;
#pragma unroll
      for (int rr = 0; rr < 4; ++rr) {
        int co = cf * 16 + l16 * 4 + rr;
        float d = acc[cf][pf][rr] - Tv[cf][rr];
        bool pos = d >= 0.f;
        if (__builtin_fabsf(d) < MARGIN1) {
          unsigned idx = atomicAdd(&cnts[0], 1u);
          if (idx < FIXCAP) fix1[idx] = make_uint2((unsigned)(n * NPIX + px0 + px_l),
                                                   (unsigned)co);
          else pos = recheck_conv1(x + (size_t)n * CI * NPIX + px0 + px_l,
                                   w1f, bn1d, co);
        }
        ldsS[px_l * 128 + (co ^ ((px_l & 7) << 2))] = pos ? 1 : 0;
      }
    }

  {
    int px = t >> 1, half = t & 1;
    const unsigned* ls = (const unsigned*)ldsS;
    u64 word = 0;
#pragma unroll
    for (int k = 0; k < 16; ++k) {
      unsigned v = ls[px * 32 + ((half * 16 + k) ^ (px & 7))];
      unsigned nib = (((v & 0x01010101u) * 0x01020408u) >> 24) & 0xFu;
      word |= (u64)nib << (4 * k);
    }
    a1b[(size_t)(n * NPIX + px0 + px) * 2 + half] = word;
  }
}

// ---------------- F1: wave-parallel f64 fixup of a1b bits ----------------
__global__ __launch_bounds__(256) void fixup1_kernel(
    const float* __restrict__ x, const float* __restrict__ w1f,
    const double* __restrict__ bn1d, const uint2* __restrict__ fix1,
    const unsigned* __restrict__ cnts, u64* __restrict__ a1b) {
  unsigned cnt = cnts[0]; if (cnt > FIXCAP) cnt = FIXCAP;
  int nw = gridDim.x * 4;
  int gw = blockIdx.x * 4 + (threadIdx.x >> 6);
  int lane = threadIdx.x & 63;
  for (unsigned i = gw; i < cnt; i += nw) {
    uint2 it = fix1[i];
    int np = (int)it.x, co = (int)it.y;
    int n = np / NPIX, p = np % NPIX;
    const float* xg = x + (size_t)n * CI * NPIX + p;
    double s = 0.0;
#pragma unroll
    for (int j = 0; j < 4; ++j) {
      int ci = lane * 4 + j;
      s = fma((double)w1f[ci * 128 + co], (double)xg[(size_t)ci * NPIX], s);
    }
    for (int off = 32; off; off >>= 1) s += __shfl_down(s, off);
    if (lane == 0) {
      double val = (s - bn1d[128 + co]) * bn1d[co] + bn1d[256 + co];
      u64* ap = a1b + (size_t)np * 2 + (co >> 6);
      u64 bit = 1ull << (co & 63);
      if (val >= 0.0) atomicOr(ap, bit); else atomicAnd(ap, ~bit);
    }
  }
}

// ---------------- K2: conv2 (3x3 s2 p1, XNOR-popcount) + bn2 + sign --------
__global__ __launch_bounds__(256) void conv2_kernel(
    const u64* __restrict__ a1b, const u64* __restrict__ w2b,
    const float* __restrict__ g2, const float* __restrict__ b2,
    const float* __restrict__ m2, const float* __restrict__ v2,
    u64* __restrict__ a2b) {
  __shared__ u64 lw2[128 * 9 * 2];   // 18432 B
  int t = threadIdx.x;
  for (int k = 0; k < 9; ++k) lw2[t * 9 + k] = w2b[t * 9 + k];
  __syncthreads();

  int bid = (int)blockIdx.x;
  int l = (bid & 7) * 784 + (bid >> 3);
  int p = l * 4 + (t >> 6);
  int lane = t & 63;
  int n = p / NOUT, r = p % NOUT;
  int ho = r / WO, wo = r % WO;

  int y0 = 0, y1 = 0;
  for (int kh = 0; kh < 3; ++kh) {
    int ih = 2 * ho - 1 + kh;
    if (ih < 0) continue;
    for (int kw = 0; kw < 3; ++kw) {
      int iw = 2 * wo - 1 + kw;
      if (iw < 0) continue;
      const u64* ap = a1b + ((size_t)(n * HH + ih) * WW + iw) * 2;
      u64 a0 = ap[0], a1v = ap[1];
      int tap = kh * 3 + kw;
      u64 wa = lw2[lane * 18 + tap * 2], wb = lw2[lane * 18 + tap * 2 + 1];
      y0 += 128 - 2 * (__popcll(a0 ^ wa) + __popcll(a1v ^ wb));
      wa = lw2[(lane + 64) * 18 + tap * 2]; wb = lw2[(lane + 64) * 18 + tap * 2 + 1];
      y1 += 128 - 2 * (__popcll(a0 ^ wa) + __popcll(a1v ^ wb));
    }
  }

  int co = lane;
  double inv = 1.0 / sqrt((double)v2[co] + 1e-5);
  bool c0 = (((double)y0 - (double)m2[co]) * ((double)g2[co] * inv) + (double)b2[co]) >= 0.0;
  co = lane + 64;
  inv = 1.0 / sqrt((double)v2[co] + 1e-5);
  bool c1 = (((double)y1 - (double)m2[co]) * ((double)g2[co] * inv) + (double)b2[co]) >= 0.0;

  u64 word0 = __ballot(c0);
  u64 word1 = __ballot(c1);
  if (lane == 0) {
    a2b[(size_t)p * 2] = word0;
    a2b[(size_t)p * 2 + 1] = word1;
  }
}

// ---------------- K3: shortcut — single wave, 64co x 112px -----------------
__global__ __launch_bounds__(64) void sc3_mfma_kernel(
    const unsigned* __restrict__ xTk2, const unsigned* __restrict__ wsck,
    const u64* __restrict__ a2b, const u64* __restrict__ w3b,
    const float* __restrict__ bn3f,
    uint2* __restrict__ fix3, unsigned* __restrict__ cnts,
    float* __restrict__ out) {
  __shared__ unsigned char ldsS[64 * 112];   // 7168 B wave-private

  int bid = (int)blockIdx.x;
  int cob = bid & 7; int r = bid >> 3;
  int pxt = r % 7, n = r / 7;
  int px0 = pxt * 112, co0 = cob * 64;
  int t = threadIdx.x;
  int l16 = t >> 4, llo = t & 15;
  int sA = (llo & 7) << 2;

  const unsigned* wb = wsck + (size_t)(co0 + llo) * 32;

  f32x4 acc[4][7] = {};

  for (int kst = 0; kst < 8; ++kst) {
    const unsigned* gb = xTk2 + ((size_t)(n * 8 + kst) * NOUT + px0) * 32;
#pragma unroll
    for (int ks = 0; ks < 2; ++ks) {
      int kb = ks * 16 + l16 * 4;
      short8v aF[4];
#pragma unroll
      for (int cf = 0; cf < 4; ++cf)
        aF[cf] = *(const short8v*)(wb + kst * 16384 + cf * 512 + (kb ^ sA));
#pragma unroll
      for (int pf = 0; pf < 7; ++pf) {
        short8v bv = *(const short8v*)(gb + (size_t)(pf * 16 + llo) * 32 + (kb ^ sA));
#pragma unroll
        for (int cf = 0; cf < 4; ++cf)
          acc[cf][pf] = __builtin_amdgcn_mfma_f32_16x16x32_bf16(aF[cf], bv, acc[cf][pf], 0, 0, 0);
      }
    }
  }

  // epilogue: conv3 popcount + fused BNs + sign (+ rare list-append)
  int pl[7];
  u64 a20[7], a21[7];
#pragma unroll
  for (int pf = 0; pf < 7; ++pf) {
    pl[pf] = px0 + pf * 16 + llo;
    const u64* ap = a2b + (size_t)(n * NOUT + pl[pf]) * 2;
    a20[pf] = ap[0]; a21[pf] = ap[1];
  }

#pragma unroll
  for (int cf = 0; cf < 4; ++cf) {
    float ssv[4], s3v[4], Cv[4];
    u64 w30[4], w31[4];
#pragma unroll
    for (int rr = 0; rr < 4; ++rr) {
      int co = co0 + cf * 16 + l16 * 4 + rr;
      ssv[rr] = bn3f[co]; s3v[rr] = bn3f[512 + co]; Cv[rr] = bn3f[1024 + co];
      w30[rr] = w3b[co * 2]; w31[rr] = w3b[co * 2 + 1];
    }
#pragma unroll
    for (int pf = 0; pf < 7; ++pf) {
#pragma unroll
      for (int rr = 0; rr < 4; ++rr) {
        int co_loc = cf * 16 + l16 * 4 + rr;
        int co = co0 + co_loc;
        int y3 = 128 - 2 * (int)(__popcll(a20[pf] ^ w30[rr]) +
                                 __popcll(a21[pf] ^ w31[rr]));
        float val = fmaf(acc[cf][pf][rr], ssv[rr],
                         fmaf((float)y3, s3v[rr], Cv[rr]));
        bool pos = val >= 0.f;
        if (__builtin_fabsf(val) < MARGIN3) {
          unsigned idx = atomicAdd(&cnts[1], 1u);
          if (idx < FIXCAP)
            fix3[idx] = make_uint2((unsigned)(n * NOUT + pl[pf]),
                                   (unsigned)co | ((unsigned)(y3 + 256) << 16));
        }
        ldsS[co_loc * 112 + (pf * 16 + llo)] = pos ? 1 : 0;
      }
    }
  }

  if (t < 56) {
    int f4 = t % 28, half = t / 28;     // 0..1
    const unsigned* ls32 = (const unsigned*)ldsS;
#pragma unroll
    for (int j = 0; j < 32; ++j) {
      int co_loc = half * 32 + j;
      unsigned wbyte = ls32[co_loc * 28 + f4];
      float4 o;
      o.x = (wbyte & 0xFFu) ? 1.f : -1.f;
      o.y = (wbyte & 0xFF00u) ? 1.f : -1.f;
      o.z = (wbyte & 0xFF0000u) ? 1.f : -1.f;
      o.w = (wbyte & 0xFF000000u) ? 1.f : -1.f;
      *(float4*)(out + ((size_t)(n * CO + co0 + co_loc)) * NOUT
                 + px0 + f4 * 4) = o;
    }
  }
}

// ---------------- F3: wave-parallel f64 fixup of out values ----------------
__global__ __launch_bounds__(256) void fixup3_kernel(
    const float* __restrict__ x, const float* __restrict__ wscf,
    const double* __restrict__ bn3d, const uint2* __restrict__ fix3,
    const unsigned* __restrict__ cnts, float* __restrict__ out) {
  unsigned cnt = cnts[1]; if (cnt > FIXCAP) cnt = FIXCAP;
  int nw = gridDim.x * 4;
  int gw = blockIdx.x * 4 + (threadIdx.x >> 6);
  int lane = threadIdx.x & 63;
  for (unsigned i = gw; i < cnt; i += nw) {
    uint2 it = fix3[i];
    int npl = (int)it.x;
    int co = (int)(it.y & 0xFFFFu);
    int y3 = (int)(it.y >> 16) - 256;
    int n = npl / NOUT, pl = npl % NOUT;
    int ho = pl / WO, wo = pl % WO;
    const float* xg = x + (size_t)n * CI * NPIX + ho * 112 + wo * 2;
    double s = 0.0;
#pragma unroll
    for (int j = 0; j < 4; ++j) {
      int ci = lane * 4 + j;
      s = fma((double)wscf[ci * 512 + co], (double)xg[(size_t)ci * NPIX], s);
    }
    for (int off = 32; off; off >>= 1) s += __shfl_down(s, off);
    if (lane == 0) {
      double val = s * bn3d[co] + (double)y3 * bn3d[512 + co] + bn3d[1024 + co];
      out[(size_t)(n * CO + co) * NOUT + pl] = (val >= 0.0) ? 1.0f : -1.0f;
    }
  }
}

// ================= fallback (R2) f32-VALU kernels =================
__global__ __launch_bounds__(256) void conv1_kernel(
    const float* __restrict__ x, const float* __restrict__ w1f,
    const float* __restrict__ T1f, const double* __restrict__ bn1d,
    u64* __restrict__ a1b) {
  __shared__ float4 xrow4[128 * WW / 4];
  __shared__ unsigned char pk[WW * 32];
  float* xrow = (float*)xrow4;

  int bid = blockIdx.x;
  int n = bid / HH, h = bid % HH;
  int t = threadIdx.x;
  int cg = t & 31, wg = t >> 5;
  int co0 = cg * 4, w0 = wg * 7;

  float acc[4][7];
#pragma unroll
  for (int c = 0; c < 4; ++c)
#pragma unroll
    for (int j = 0; j < 7; ++j) acc[c][j] = 0.f;

  for (int chunk = 0; chunk < 2; ++chunk) {
    const float4* xsrc = (const float4*)(x + (size_t)n * CI * NPIX
                                         + (size_t)chunk * 128 * NPIX + h * WW);
    for (int i = 0; i < 7; ++i) {
      int idx = i * 256 + t;
      int ci = idx / 14, f = idx % 14;
      xrow4[ci * 14 + f] = xsrc[(size_t)ci * (NPIX / 4) + f];
    }
    __syncthreads();

    const float* wp = w1f + (size_t)chunk * 128 * 128 + co0;
#pragma unroll 2
    for (int ci = 0; ci < 128; ++ci) {
      float4 wv = *(const float4*)(wp + ci * 128);
      const float* xr = xrow + ci * WW + w0;
#pragma unroll
      for (int j = 0; j < 7; ++j) {
        float xv = xr[j];
        acc[0][j] = fmaf(wv.x, xv, acc[0][j]);
        acc[1][j] = fmaf(wv.y, xv, acc[1][j]);
        acc[2][j] = fmaf(wv.z, xv, acc[2][j]);
        acc[3][j] = fmaf(wv.w, xv, acc[3][j]);
      }
    }
    __syncthreads();
  }

  float Tv[4];
#pragma unroll
  for (int c = 0; c < 4; ++c) Tv[c] = T1f[co0 + c];

  for (int j = 0; j < 7; ++j) {
    unsigned nib = 0;
    for (int c = 0; c < 4; ++c) {
      float d = acc[c][j] - Tv[c];
      bool pos;
      if (__builtin_fabsf(d) >= 1e-2f) pos = d >= 0.f;
      else pos = recheck_conv1(x + (size_t)n * CI * NPIX + h * WW + (w0 + j),
                               w1f, bn1d, co0 + c);
      nib |= ((unsigned)pos) << c;
    }
    pk[(w0 + j) * 32 + cg] = (unsigned char)nib;
  }
  __syncthreads();

  if (t < 112) {
    int w = t >> 1, half = t & 1;
    u64 word = 0;
    for (int k = 0; k < 16; ++k)
      word |= ((u64)pk[w * 32 + half * 16 + k]) << (4 * k);
    a1b[((size_t)(n * HH + h) * WW + w) * 2 + half] = word;
  }
}

__global__ __launch_bounds__(256) void sc3_kernel(
    const float* __restrict__ x, const float* __restrict__ wscf,
    const u64* __restrict__ a2b, const u64* __restrict__ w3b,
    const float* __restrict__ bn3f, const double* __restrict__ bn3d,
    float* __restrict__ out) {
  __shared__ float4 xrow4[128 * WW / 4];
  __shared__ u64 a2row[WO * 2];
  float* xrow = (float*)xrow4;

  int bid = blockIdx.x;
  int half = bid & 1;
  int tmp = bid >> 1;
  int n = tmp / HO, ho = tmp % HO;
  int t = threadIdx.x;
  int cg = t & 63, wg = t >> 6;
  int co0 = half * 256 + cg * 4, w0 = wg * 7;

  if (t < 56)
    a2row[t] = a2b[((size_t)(n * HO + ho) * WO + (t >> 1)) * 2 + (t & 1)];

  float acc[4][7];
#pragma unroll
  for (int c = 0; c < 4; ++c)
#pragma unroll
    for (int j = 0; j < 7; ++j) acc[c][j] = 0.f;

  for (int chunk = 0; chunk < 2; ++chunk) {
    const float4* xsrc = (const float4*)(x + (size_t)n * CI * NPIX
                                         + (size_t)chunk * 128 * NPIX
                                         + (2 * ho) * WW);
    for (int i = 0; i < 7; ++i) {
      int idx = i * 256 + t;
      int ci = idx / 14, f = idx % 14;
      xrow4[ci * 14 + f] = xsrc[(size_t)ci * (NPIX / 4) + f];
    }
    __syncthreads();

    const float* wp = wscf + (size_t)chunk * 128 * 512 + co0;
#pragma unroll 2
    for (int ci = 0; ci < 128; ++ci) {
      float4 wv = *(const float4*)(wp + ci * 512);
      const float* xr = xrow + ci * WW + 2 * w0;
#pragma unroll
      for (int j = 0; j < 7; ++j) {
        float xv = xr[2 * j];
        acc[0][j] = fmaf(wv.x, xv, acc[0][j]);
        acc[1][j] = fmaf(wv.y, xv, acc[1][j]);
        acc[2][j] = fmaf(wv.z, xv, acc[2][j]);
        acc[3][j] = fmaf(wv.w, xv, acc[3][j]);
      }
    }
    __syncthreads();
  }

#pragma unroll
  for (int c = 0; c < 4; ++c) {
    int co = co0 + c;
    u64 w30 = w3b[co * 2], w31 = w3b[co * 2 + 1];
    float ssf = bn3f[co], s3f = bn3f[512 + co], Cf = bn3f[1024 + co];
    float* op = out + ((size_t)(n * CO + co) * NOUT) + ho * WO + w0;
    for (int j = 0; j < 7; ++j) {
      int wo = w0 + j;
      u64 a0 = a2row[wo * 2], a1v = a2row[wo * 2 + 1];
      int y3 = 128 - 2 * (int)(__popcll(a0 ^ w30) + __popcll(a1v ^ w31));
      float val = fmaf(acc[c][j], ssf, fmaf((float)y3, s3f, Cf));
      bool pos;
      if (__builtin_fabsf(val) >= 2e-2f) pos = val >= 0.f;
      else pos = recheck_sc3(x + (size_t)n * CI * NPIX + (2 * ho) * WW + 2 * wo,
                             wscf, bn3d, co, y3);
      op[j] = pos ? 1.0f : -1.0f;
    }
  }
}

extern "C" void kernel_launch(void* const* d_in, const int* in_sizes, int n_in,
                              void* d_out, int out_size, void* d_ws, size_t ws_size,
                              hipStream_t stream) {
  const float* x   = (const float*)d_in[0];
  const float* W1  = (const float*)d_in[1];
  const float* W2  = (const float*)d_in[2];
  const float* W3  = (const float*)d_in[3];
  const float* Wsc = (const float*)d_in[4];
  const float* g1 = (const float*)d_in[5],  *b1 = (const float*)d_in[6];
  const float* m1 = (const float*)d_in[7],  *v1 = (const float*)d_in[8];
  const float* g2 = (const float*)d_in[9],  *b2 = (const float*)d_in[10];
  const float* m2 = (const float*)d_in[11], *v2 = (const float*)d_in[12];
  const float* g3 = (const float*)d_in[13], *b3 = (const float*)d_in[14];
  const float* m3 = (const float*)d_in[15], *v3 = (const float*)d_in[16];
  const float* gs = (const float*)d_in[17], *bs = (const float*)d_in[18];
  const float* ms = (const float*)d_in[19], *vs = (const float*)d_in[20];

  char* ws = (char*)d_ws;
  float*  w1f  = (float*)(ws + 0);           // 131072
  float*  wscf = (float*)(ws + 131072);      // 524288
  u64*    a1b  = (u64*)(ws + 655360);        // 1605632
  u64*    a2b  = (u64*)(ws + 2260992);       // 401408
  u64*    w2b  = (u64*)(ws + 2662400);       // 18432
  u64*    w3b  = (u64*)(ws + 2680832);       // 8192
  float*  T1f  = (float*)(ws + 2689024);     // 512
  double* bn1d = (double*)(ws + 2689536);    // 3072
  float*  bn3f = (float*)(ws + 2692608);     // 6144
  double* bn3d = (double*)(ws + 2698752);    // 12288
  unsigned* w1k  = (unsigned*)(ws + 2711040);    // 131072
  unsigned* wsck = (unsigned*)(ws + 2842112);    // 524288
  unsigned* xTk2 = (unsigned*)(ws + 3366400);    // 25690112
  uint2*    fix1 = (uint2*)(ws + 29056512);      // 524288
  uint2*    fix3 = (uint2*)(ws + 29580800);      // 524288
  unsigned* cnts = (unsigned*)(ws + 30105088);   // 256
  const size_t required = 30105344ull;           // ~28.7 MiB
  float* out = (float*)d_out;

  bool mfma_path = (ws_size >= required);
  if (!mfma_path) {   // alias mfma-only arrays into a1b region (unused then)
    w1k  = (unsigned*)a1b;
    wsck = (unsigned*)a1b + 32768;
    cnts = (unsigned*)a1b + 32768 + 131072;
  }

  hipLaunchKernelGGL(pack_kernel, dim3(2115), dim3(256), 0, stream,
                     W1, W2, W3, Wsc, g1, b1, m1, v1, g3, b3, m3, v3,
                     gs, bs, ms, vs, w1f, wscf, w2b, w3b, T1f, bn1d, bn3f, bn3d,
                     w1k, wsck, cnts);
  if (mfma_path) {
    hipLaunchKernelGGL(conv1_mfma_kernel, dim3(NB * 98), dim3(64), 0, stream,
                       x, w1k, w1f, T1f, bn1d, fix1, cnts, a1b, xTk2);
    hipLaunchKernelGGL(fixup1_kernel, dim3(256), dim3(256), 0, stream,
                       x, w1f, bn1d, fix1, cnts, a1b);
    hipLaunchKernelGGL(conv2_kernel, dim3(NB * NOUT / 4), dim3(256), 0, stream,
                       a1b, w2b, g2, b2, m2, v2, a2b);
    hipLaunchKernelGGL(sc3_mfma_kernel, dim3(NB * 7 * 8), dim3(64), 0, stream,
                       xTk2, wsck, a2b, w3b, bn3f, fix3, cnts, out);
    hipLaunchKernelGGL(fixup3_kernel, dim3(256), dim3(256), 0, stream,
                       x, wscf, bn3d, fix3, cnts, out);
  } else {
    hipLaunchKernelGGL(conv1_kernel, dim3(NB * HH), dim3(256), 0, stream,
                       x, w1f, T1f, bn1d, a1b);
    hipLaunchKernelGGL(conv2_kernel, dim3(NB * NOUT / 4), dim3(256), 0, stream,
                       a1b, w2b, g2, b2, m2, v2, a2b);
    hipLaunchKernelGGL(sc3_kernel, dim3(NB * HO * 2), dim3(256), 0, stream,
                       x, wscf, a2b, w3b, bn3f, bn3d, out);
  }
}